// Round 1
// baseline (178.713 us; speedup 1.0000x reference)
//
#include <hip/hip_runtime.h>

#define HW   3136
#define HW4  784
#define B    32
#define C    256
#define CS   64
#define EPS  1e-5f

// ---------------- Kernel 1: global average pool ----------------
// One block per (b,c). 3136 floats = 784 float4 per block.
__global__ __launch_bounds__(256) void se_pool(const float* __restrict__ x,
                                               float* __restrict__ s) {
    const int bc = blockIdx.x;  // 0..8191
    const float4* xp = (const float4*)(x + (size_t)bc * HW);
    float sum = 0.f;
    for (int i = threadIdx.x; i < HW4; i += 256) {
        float4 v = xp[i];
        sum += (v.x + v.y) + (v.z + v.w);
    }
    // wave64 reduce
    for (int off = 32; off; off >>= 1) sum += __shfl_down(sum, off, 64);
    __shared__ float red[4];
    const int lane = threadIdx.x & 63;
    const int wid  = threadIdx.x >> 6;
    if (lane == 0) red[wid] = sum;
    __syncthreads();
    if (threadIdx.x == 0) {
        float t = (red[0] + red[1]) + (red[2] + red[3]);
        s[bc] = t * (1.0f / (float)HW);
    }
}

// ---------------- Kernel 2: tiny MLP (1x1 convs + BN + act) ----------------
// Single block, 256 threads. h (32x64) staged in LDS.
__global__ __launch_bounds__(256) void se_mlp(
        const float* __restrict__ s,
        const float* __restrict__ w1,
        const float* __restrict__ bn1_gamma, const float* __restrict__ bn1_beta,
        const float* __restrict__ bn1_mean,  const float* __restrict__ bn1_var,
        const float* __restrict__ w2,
        const float* __restrict__ bn2_gamma, const float* __restrict__ bn2_beta,
        const float* __restrict__ bn2_mean,  const float* __restrict__ bn2_var,
        float* __restrict__ g) {
    __shared__ float h_lds[B * CS];  // 2048 floats = 8 KB
    const int t = threadIdx.x;

    // h[b][cs] = dot(s[b,:], w1[cs,:]) -> BN1 -> ReLU
    for (int i = t; i < B * CS; i += 256) {
        const int b  = i / CS;
        const int cs = i % CS;
        const float* sp = s  + b  * C;
        const float* wp = w1 + cs * C;
        float acc = 0.f;
        #pragma unroll 4
        for (int k = 0; k < C; k += 4) {
            float4 sv = *(const float4*)(sp + k);
            float4 wv = *(const float4*)(wp + k);
            acc += sv.x * wv.x + sv.y * wv.y + sv.z * wv.z + sv.w * wv.w;
        }
        const float scale = bn1_gamma[cs] * rsqrtf(bn1_var[cs] + EPS);
        float v = (acc - bn1_mean[cs]) * scale + bn1_beta[cs];
        h_lds[i] = fmaxf(v, 0.f);
    }
    __syncthreads();

    // g[b][c] = dot(h[b,:], w2[c,:]) -> BN2 -> hsigmoid
    for (int i = t; i < B * C; i += 256) {
        const int b = i / C;
        const int c = i % C;
        const float* hp = h_lds + b * CS;
        const float* wp = w2    + c * CS;
        float acc = 0.f;
        #pragma unroll 4
        for (int k = 0; k < CS; k += 4) {
            float4 hv = *(const float4*)(hp + k);
            float4 wv = *(const float4*)(wp + k);
            acc += hv.x * wv.x + hv.y * wv.y + hv.z * wv.z + hv.w * wv.w;
        }
        const float scale = bn2_gamma[c] * rsqrtf(bn2_var[c] + EPS);
        float v = (acc - bn2_mean[c]) * scale + bn2_beta[c];
        v = fminf(fmaxf(v + 3.f, 0.f), 6.f) * (1.f / 6.f);
        g[i] = v;
    }
}

// ---------------- Kernel 3: excite (broadcast multiply) ----------------
__global__ __launch_bounds__(256) void se_scale(const float* __restrict__ x,
                                                const float* __restrict__ g,
                                                float* __restrict__ out) {
    const unsigned total4 = (unsigned)B * C * HW4;  // 6,422,528
    for (unsigned i = blockIdx.x * 256u + threadIdx.x; i < total4;
         i += gridDim.x * 256u) {
        const unsigned bc = i / HW4;   // magic-mul division by 784
        const float gv = g[bc];
        float4 v = ((const float4*)x)[i];
        v.x *= gv; v.y *= gv; v.z *= gv; v.w *= gv;
        ((float4*)out)[i] = v;
    }
}

extern "C" void kernel_launch(void* const* d_in, const int* in_sizes, int n_in,
                              void* d_out, int out_size, void* d_ws, size_t ws_size,
                              hipStream_t stream) {
    const float* x         = (const float*)d_in[0];
    const float* w1        = (const float*)d_in[1];
    const float* bn1_gamma = (const float*)d_in[2];
    const float* bn1_beta  = (const float*)d_in[3];
    const float* bn1_mean  = (const float*)d_in[4];
    const float* bn1_var   = (const float*)d_in[5];
    const float* w2        = (const float*)d_in[6];
    const float* bn2_gamma = (const float*)d_in[7];
    const float* bn2_beta  = (const float*)d_in[8];
    const float* bn2_mean  = (const float*)d_in[9];
    const float* bn2_var   = (const float*)d_in[10];
    float* out = (float*)d_out;

    float* s = (float*)d_ws;          // 8192 floats
    float* g = s + B * C;             // 8192 floats

    se_pool<<<B * C, 256, 0, stream>>>(x, s);
    se_mlp<<<1, 256, 0, stream>>>(s, w1, bn1_gamma, bn1_beta, bn1_mean, bn1_var,
                                  w2, bn2_gamma, bn2_beta, bn2_mean, bn2_var, g);
    se_scale<<<2048, 256, 0, stream>>>(x, g, out);
}

// Round 2
// 59.182 us; speedup vs baseline: 3.0197x; 3.0197x over previous
//
#include <hip/hip_runtime.h>

#define HW   3136
#define HW4  784
#define B    32
#define C    256
#define CS   64
#define EPS  1e-5f

// ---------------- Kernel 1: global average pool ----------------
// One block per (b,c). 3136 floats = 784 float4 per block.
__global__ __launch_bounds__(256) void se_pool(const float* __restrict__ x,
                                               float* __restrict__ s) {
    const int bc = blockIdx.x;  // 0..8191
    const float4* xp = (const float4*)(x + (size_t)bc * HW);
    float sum = 0.f;
    for (int i = threadIdx.x; i < HW4; i += 256) {
        float4 v = xp[i];
        sum += (v.x + v.y) + (v.z + v.w);
    }
    // wave64 reduce
    for (int off = 32; off; off >>= 1) sum += __shfl_down(sum, off, 64);
    __shared__ float red[4];
    const int lane = threadIdx.x & 63;
    const int wid  = threadIdx.x >> 6;
    if (lane == 0) red[wid] = sum;
    __syncthreads();
    if (threadIdx.x == 0) {
        float t = (red[0] + red[1]) + (red[2] + red[3]);
        s[bc] = t * (1.0f / (float)HW);
    }
}

// ---------------- Kernel 2a: h = ReLU(BN1(s @ w1^T)) ----------------
// One wave per output element. 2048 outputs -> 512 blocks x 4 waves.
__global__ __launch_bounds__(256) void se_mlp1(
        const float* __restrict__ s,
        const float* __restrict__ w1,
        const float* __restrict__ bn1_gamma, const float* __restrict__ bn1_beta,
        const float* __restrict__ bn1_mean,  const float* __restrict__ bn1_var,
        float* __restrict__ h) {
    const int o    = blockIdx.x * 4 + (threadIdx.x >> 6);  // 0..2047
    const int lane = threadIdx.x & 63;
    const int b  = o >> 6;   // /CS
    const int cs = o & 63;   // %CS
    const float* sp = s  + b  * C;
    const float* wp = w1 + cs * C;
    float acc = 0.f;
    #pragma unroll
    for (int k = 0; k < 4; ++k) {
        const int idx = lane + k * 64;
        acc += sp[idx] * wp[idx];
    }
    #pragma unroll
    for (int off = 32; off; off >>= 1) acc += __shfl_down(acc, off, 64);
    if (lane == 0) {
        const float scale = bn1_gamma[cs] * rsqrtf(bn1_var[cs] + EPS);
        float v = (acc - bn1_mean[cs]) * scale + bn1_beta[cs];
        h[o] = fmaxf(v, 0.f);
    }
}

// ---------------- Kernel 2b: g = hsigmoid(BN2(h @ w2^T)) ----------------
// One block per batch row; one thread per output channel.
__global__ __launch_bounds__(256) void se_mlp2(
        const float* __restrict__ h,
        const float* __restrict__ w2,
        const float* __restrict__ bn2_gamma, const float* __restrict__ bn2_beta,
        const float* __restrict__ bn2_mean,  const float* __restrict__ bn2_var,
        float* __restrict__ g) {
    __shared__ float hb[CS];
    const int b = blockIdx.x;
    const int c = threadIdx.x;
    if (c < CS) hb[c] = h[b * CS + c];
    __syncthreads();
    const float* wp = w2 + c * CS;
    float acc = 0.f;
    #pragma unroll
    for (int k = 0; k < CS; k += 4) {
        float4 wv = *(const float4*)(wp + k);
        acc += wv.x * hb[k] + wv.y * hb[k + 1] + wv.z * hb[k + 2] + wv.w * hb[k + 3];
    }
    const float scale = bn2_gamma[c] * rsqrtf(bn2_var[c] + EPS);
    float v = (acc - bn2_mean[c]) * scale + bn2_beta[c];
    v = fminf(fmaxf(v + 3.f, 0.f), 6.f) * (1.f / 6.f);
    g[b * C + c] = v;
}

// ---------------- Kernel 3: excite (broadcast multiply) ----------------
__global__ __launch_bounds__(256) void se_scale(const float* __restrict__ x,
                                                const float* __restrict__ g,
                                                float* __restrict__ out) {
    const unsigned total4 = (unsigned)B * C * HW4;  // 6,422,528
    for (unsigned i = blockIdx.x * 256u + threadIdx.x; i < total4;
         i += gridDim.x * 256u) {
        const unsigned bc = i / HW4;
        const float gv = g[bc];
        float4 v = ((const float4*)x)[i];
        v.x *= gv; v.y *= gv; v.z *= gv; v.w *= gv;
        ((float4*)out)[i] = v;
    }
}

extern "C" void kernel_launch(void* const* d_in, const int* in_sizes, int n_in,
                              void* d_out, int out_size, void* d_ws, size_t ws_size,
                              hipStream_t stream) {
    const float* x         = (const float*)d_in[0];
    const float* w1        = (const float*)d_in[1];
    const float* bn1_gamma = (const float*)d_in[2];
    const float* bn1_beta  = (const float*)d_in[3];
    const float* bn1_mean  = (const float*)d_in[4];
    const float* bn1_var   = (const float*)d_in[5];
    const float* w2        = (const float*)d_in[6];
    const float* bn2_gamma = (const float*)d_in[7];
    const float* bn2_beta  = (const float*)d_in[8];
    const float* bn2_mean  = (const float*)d_in[9];
    const float* bn2_var   = (const float*)d_in[10];
    float* out = (float*)d_out;

    float* s = (float*)d_ws;          // 8192 floats
    float* h = s + B * C;             // 2048 floats
    float* g = h + B * CS;            // 8192 floats

    se_pool<<<B * C, 256, 0, stream>>>(x, s);
    se_mlp1<<<(B * CS) / 4, 256, 0, stream>>>(s, w1, bn1_gamma, bn1_beta,
                                              bn1_mean, bn1_var, h);
    se_mlp2<<<B, 256, 0, stream>>>(h, w2, bn2_gamma, bn2_beta,
                                   bn2_mean, bn2_var, g);
    se_scale<<<2048, 256, 0, stream>>>(x, g, out);
}